// Round 1
// baseline (88.442 us; speedup 1.0000x reference)
//
#include <hip/hip_runtime.h>

// DownscaleLabel: label [16,1024,1024] int32 in [-1,6] -> out [16,1,64,64] int32.
// Per 16x16 block: class histogram (-1 -> class 7), first-argmax over 8 classes,
// -1 if dominant class==7 or max count < 192 (0.75*256).
//
// One 64-lane wave per output block. Lane l loads int4 at (row=l>>2, col=(l&3)*4):
// each 64B line consumed by exactly 4 lanes, every input byte read once.
// Histogram: 8 classes x 8-bit packed in one u64; butterfly-xor reduce offsets
// 1..16 (max 128 per field, no overflow), widen to 16-bit fields for the final
// offset-32 step (max 256).

__global__ __launch_bounds__(256) void downscale_label_kernel(
    const int* __restrict__ label, int* __restrict__ out) {
  const int tid  = threadIdx.x;
  const int lane = tid & 63;
  const int o    = (blockIdx.x << 2) + (tid >> 6);  // output block id, < 65536

  const int b  = o >> 12;          // batch (th*tw = 64*64 = 4096)
  const int ty = (o >> 6) & 63;    // tile row
  const int tx = o & 63;           // tile col

  const int row = lane >> 2;       // 0..15 within tile
  const int col = (lane & 3) << 2; // 0,4,8,12 within tile

  // flat input index (max ~16.7M, fits int)
  const int idx = ((((b << 6) + ty) << 4) + row) * 1024 + (tx << 4) + col;
  const int4 v = *(const int4*)(label + idx);

  // map -1 -> 7 via (v+8)&7; accumulate packed 8x8-bit histogram
  unsigned long long acc = 0;
  acc += 1ULL << (((v.x + 8) & 7) << 3);
  acc += 1ULL << (((v.y + 8) & 7) << 3);
  acc += 1ULL << (((v.z + 8) & 7) << 3);
  acc += 1ULL << (((v.w + 8) & 7) << 3);

  // butterfly over 32 lanes in 8-bit fields (max 32 lanes * 4 = 128 < 256)
  #pragma unroll
  for (int off = 1; off <= 16; off <<= 1)
    acc += __shfl_xor(acc, off, 64);

  // widen to 16-bit fields: even holds classes 0,2,4,6; odd holds 1,3,5,7
  const unsigned long long M = 0x00FF00FF00FF00FFULL;
  unsigned long long even = acc & M;
  unsigned long long odd  = (acc >> 8) & M;
  even += __shfl_xor(even, 32, 64);
  odd  += __shfl_xor(odd,  32, 64);

  if (lane == 0) {
    int best = -1, bi = 0;
    #pragma unroll
    for (int k = 0; k < 8; ++k) {
      const unsigned long long src = (k & 1) ? odd : even;
      const int c = (int)((src >> ((k >> 1) << 4)) & 0xFFFF);
      if (c > best) { best = c; bi = k; }   // strict > == first-max tie-break
    }
    out[o] = (bi == 7 || best < 192) ? -1 : bi;
  }
}

extern "C" void kernel_launch(void* const* d_in, const int* in_sizes, int n_in,
                              void* d_out, int out_size, void* d_ws, size_t ws_size,
                              hipStream_t stream) {
  const int* label = (const int*)d_in[0];
  int* out = (int*)d_out;
  // 65536 output blocks, 4 waves (=4 blocks) per 256-thread workgroup
  downscale_label_kernel<<<16384, 256, 0, stream>>>(label, out);
}

// Round 2
// 86.325 us; speedup vs baseline: 1.0245x; 1.0245x over previous
//
#include <hip/hip_runtime.h>

// DownscaleLabel: label [16,1024,1024] int32 in [-1,6] -> out [16,1,64,64] int32.
// Per 16x16 block: class histogram (-1 -> class 7), first-argmax over 8 classes,
// -1 if dominant class==7 or max count < 192 (0.75*256).
//
// One 256-thread workgroup per (batch, tile-row) strip: 16 consecutive rows =
// 64 KiB contiguous. Thread t loads int4 at col 4t of each of the 16 rows ->
// every load instruction covers 4 KiB contiguous (perfect coalescing), 16
// independent loads per thread for latency hiding. Thread t accumulates only
// into tile t/4, so cross-lane reduction is just offsets {1,2}.
// Histogram packed 8 classes x 8-bit in one u64 (per-thread max 64/class);
// offset-1 butterfly in 8-bit fields (max 128), widen to 16-bit, offset-2
// butterfly (max 256).

__global__ __launch_bounds__(256) void downscale_label_kernel(
    const int* __restrict__ label, int* __restrict__ out) {
  const int t = threadIdx.x;        // 0..255
  const int g = blockIdx.x;         // 0..1023 == b*64 + ty
  const int base = (g << 14) + (t << 2);  // strip is 16384 elems, contiguous

  unsigned long long acc = 0;
  #pragma unroll
  for (int i = 0; i < 16; ++i) {
    const int4 v = *(const int4*)(label + base + (i << 10));
    acc += 1ULL << (((v.x + 8) & 7) << 3);   // -1 -> class 7
    acc += 1ULL << (((v.y + 8) & 7) << 3);
    acc += 1ULL << (((v.z + 8) & 7) << 3);
    acc += 1ULL << (((v.w + 8) & 7) << 3);
  }

  // reduce across the 4 threads sharing tile t/4
  acc += __shfl_xor(acc, 1, 64);                      // 8-bit fields, max 128
  const unsigned long long M = 0x00FF00FF00FF00FFULL;
  unsigned long long even = acc & M;                  // classes 0,2,4,6
  unsigned long long odd  = (acc >> 8) & M;           // classes 1,3,5,7
  even += __shfl_xor(even, 2, 64);                    // 16-bit fields, max 256
  odd  += __shfl_xor(odd,  2, 64);

  if ((t & 3) == 0) {
    int best = -1, bi = 0;
    #pragma unroll
    for (int k = 0; k < 8; ++k) {
      const unsigned long long src = (k & 1) ? odd : even;
      const int c = (int)((src >> ((k >> 1) << 4)) & 0xFFFF);
      if (c > best) { best = c; bi = k; }   // strict > == first-max tie-break
    }
    out[(g << 6) + (t >> 2)] = (bi == 7 || best < 192) ? -1 : bi;
  }
}

extern "C" void kernel_launch(void* const* d_in, const int* in_sizes, int n_in,
                              void* d_out, int out_size, void* d_ws, size_t ws_size,
                              hipStream_t stream) {
  const int* label = (const int*)d_in[0];
  int* out = (int*)d_out;
  // 16 batches * 64 tile-rows = 1024 workgroups (4 per CU), 256 threads each
  downscale_label_kernel<<<1024, 256, 0, stream>>>(label, out);
}